// Round 16
// baseline (419.730 us; speedup 1.0000x reference)
//
#include <hip/hip_runtime.h>
#include <hip/hip_bf16.h>
#include <math.h>

#define DI __device__ __forceinline__

namespace {

constexpr int L = 4096;
constexpr float EPS = 1e-5f;
constexpr float SCALEF = 0.08838834764831845f;  // 128^-0.5

typedef unsigned short u16;
typedef unsigned int u32;
typedef unsigned char u8;
typedef __attribute__((ext_vector_type(8))) short bf16x8;
typedef __attribute__((ext_vector_type(4))) float f32x4;

DI float b2f(u16 h){ u32 u = ((u32)h) << 16; float f; __builtin_memcpy(&f, &u, 4); return f; }
DI u16 f2b(float f){ u32 u; __builtin_memcpy(&u, &f, 4); u32 r = u + 0x7fffu + ((u >> 16) & 1u); return (u16)(r >> 16); }
DI float sigmoidf(float x){ return 1.f / (1.f + __expf(-x)); }

DI uint2 pack_fp8x8(const float* v){
  u32 lo = __builtin_amdgcn_cvt_pk_fp8_f32(v[0], v[1], 0, false);
  lo = (u32)__builtin_amdgcn_cvt_pk_fp8_f32(v[2], v[3], lo, true);
  u32 hi = __builtin_amdgcn_cvt_pk_fp8_f32(v[4], v[5], 0, false);
  hi = (u32)__builtin_amdgcn_cvt_pk_fp8_f32(v[6], v[7], hi, true);
  return make_uint2(lo, hi);
}
DI u8 f2e(float v){ return (u8)__builtin_amdgcn_cvt_pk_fp8_f32(v, v, 0, false); }
DI float e2f(u8 c){ return __builtin_amdgcn_cvt_f32_fp8((int)c, 0); }

// bf16 B-frag packed tile offset (o = output col, d8 = k-chunk), u16 units
DI int boff(int o, int d8){ return ((o >> 4) << 11) + (d8 << 7) + (((o & 15) ^ d8) << 3); }
// fp8 frag-major offset (A tiles 64x128: g=x>>4; B tiles 128x128: g=o>>4), bytes
DI int foff(int g, int k8, int nn){ return (g << 11) + (k8 << 7) + (nn << 3); }
// fp8 A-tile element address (x 0..63, e 0..127), bytes
DI int faddr(int x, int e){ return ((x >> 4) << 11) + ((e >> 3) << 7) + ((x & 15) << 3) + (e & 7); }
// fp8 transposed [d][x] tile offset (dhi=d>>4, nl=d&15, x8=x>>3), bytes
DI int t8off(int dhi, int nl, int x8){ return (dhi << 11) + (x8 << 7) + (((nl ^ x8 ^ dhi) & 15) << 3); }

// ---------------------------------------------------------------- prep: LN1 (blocks 0-511) + weight pack (blocks 512-581)
__global__ __launch_bounds__(256) void prep_kernel(
    const float* __restrict__ x, const float* __restrict__ ln1_g,
    const float* __restrict__ ln1_b, u16* __restrict__ xnb,
    const float* __restrict__ q_pw, const float* __restrict__ k_pw,
    const float* __restrict__ v_pw, const float* __restrict__ out_w,
    const float* __restrict__ ff_w1, const float* __restrict__ ff_w2,
    const float* __restrict__ dwc_dw, const float* __restrict__ dwc_bng,
    const float* __restrict__ dwc_bnv, const float* __restrict__ dwc_bnb,
    const float* __restrict__ dwc_bnm, const float* __restrict__ dwc_pw,
    u16* __restrict__ wpk, float* __restrict__ c2, u8* __restrict__ wpk8)
{
  const int tid = threadIdx.x;
  if (blockIdx.x < 512){
    const int pos = blockIdx.x * 64 + (tid >> 2);
    const int part = tid & 3;
    const int b = pos >> 12, l = pos & (L - 1);
    const float* xb = x + (size_t)b * 128 * L + l;
    float vv[32];
    float s = 0.f, ss = 0.f;
    #pragma unroll
    for (int i = 0; i < 32; i++){
      float v = xb[(size_t)(part * 32 + i) * L];
      vv[i] = v; s += v; ss += v * v;
    }
    s += __shfl_xor(s, 1);  s += __shfl_xor(s, 2);
    ss += __shfl_xor(ss, 1); ss += __shfl_xor(ss, 2);
    const float m = s * (1.f / 128.f);
    const float rs = rsqrtf(ss * (1.f / 128.f) - m * m + EPS);
    #pragma unroll
    for (int c = 0; c < 4; c++){
      u16 pk[8];
      #pragma unroll
      for (int j = 0; j < 8; j++){
        int d = part * 32 + c * 8 + j;
        pk[j] = f2b((vv[c * 8 + j] - m) * rs * ln1_g[d] + ln1_b[d]);
      }
      uint4 uu; __builtin_memcpy(&uu, pk, 16);
      *(uint4*)&xnb[(size_t)pos * 128 + part * 32 + c * 8] = uu;
    }
    return;
  }
  const int blk = blockIdx.x - 512;
  if (blk < 37){
    int t8 = blk;
    #pragma unroll
    for (int it = 0; it < 8; it++){
      int item = tid + 256 * it;   // 2048: os(8)*256 + k8(16)*16 + nn(16)
      int nn = item & 15, k8 = (item >> 4) & 15, os = item >> 8;
      int o = os * 16 + nn;
      float fv[8];
      if (t8 < 24){
        int p = t8 >> 3, h = t8 & 7;
        const float* pw = (p == 0) ? q_pw : (p == 1 ? k_pw : v_pw);
        #pragma unroll
        for (int j = 0; j < 8; j++)
          fv[j] = pw[(size_t)(h * 128 + o) * 128 + k8 * 8 + j] * 16.f;
      } else if (t8 < 32){
        #pragma unroll
        for (int j = 0; j < 8; j++)
          fv[j] = out_w[(size_t)o * 1024 + (t8 - 24) * 128 + k8 * 8 + j] * 16.f;
      } else if (t8 < 36){
        #pragma unroll
        for (int j = 0; j < 8; j++)
          fv[j] = ff_w1[(size_t)((t8 - 32) * 128 + o) * 128 + k8 * 8 + j] * 16.f;
      } else {
        #pragma unroll
        for (int j = 0; j < 8; j++){
          int d = k8 * 8 + j;
          float sD = dwc_bng[d] * rsqrtf(dwc_bnv[d] + EPS);
          fv[j] = dwc_pw[(size_t)o * 128 + d] * dwc_dw[d] * sD * 16.f;
        }
      }
      *(uint2*)&wpk8[(size_t)t8 * 16384 + foff(os, k8, nn)] = pack_fp8x8(fv);
    }
  } else if (blk < 69){
    int vitem = (blk - 37) * 256 + tid;   // 8192 over 4 tiles
    int d8 = vitem & 15;
    int o  = (vitem >> 4) & 127;
    int t  = 36 + (vitem >> 11);
    const float* src = ff_w2 + (size_t)o * 512 + (t - 36) * 128 + d8 * 8;
    u16 pk[8];
    #pragma unroll
    for (int j = 0; j < 8; j++) pk[j] = f2b(src[j]);
    uint4 uu; __builtin_memcpy(&uu, pk, 16);
    *(uint4*)&wpk[(size_t)t * 16384 + boff(o, d8)] = uu;
  } else {
    int e = tid;
    if (e < 128){
      float cacc = 0.f;
      for (int d = 0; d < 128; d++){
        float sD = dwc_bng[d] * rsqrtf(dwc_bnv[d] + EPS);
        cacc += dwc_pw[(size_t)e * 128 + d] * (dwc_bnb[d] - dwc_bnm[d] * sD);
      }
      c2[e] = cacc;
    }
  }
}

// ---------------------------------------------------------------- fused qkv: dwconv+BN -> fp8 MFMA -> (softmax k) -> direct fp8 epilogue
struct QkvArgs {
  const float* dw[3];
  const float* bng[3];
  const float* bnb[3];
  const float* bnm[3];
  const float* bnv[3];
  u8* outp[3];
};

__global__ __launch_bounds__(256, 5) void qkv_fused_kernel(
    const u16* __restrict__ xnb, const u8* __restrict__ wpk8, QkvArgs args)
{
  __shared__ __attribute__((aligned(16))) u8 y_s8[64 * 136];   // fp8 A tile
  __shared__ __attribute__((aligned(16))) u8 w_s8[16384];      // fp8 B tile; aliased as st8
  __shared__ float4 coef[128];
  const int tid = threadIdx.x;
  const int lb = blockIdx.x;   // 0..63
  const int bz = blockIdx.y;   // 0..23
  const int b  = bz / 3;
  const int p  = bz % 3;
  const int l0 = lb * 64;
  const int lane = tid & 63, wv = tid >> 6;
  const int nn = lane & 15, quad = lane >> 4;
  const int d8s = tid & 15;

  if (tid < 128){
    int d = tid;
    float sD = args.bng[p][d] * rsqrtf(args.bnv[p][d] + EPS);
    const float* dw = args.dw[p];
    coef[d] = make_float4(dw[d * 3] * sD, dw[d * 3 + 1] * sD, dw[d * 3 + 2] * sD,
                          args.bnb[p][d] - args.bnm[p][d] * sD);
  }
  __syncthreads();
  float4 cf[8];
  #pragma unroll
  for (int jj = 0; jj < 8; jj++) cf[jj] = coef[d8s * 8 + jj];
  #pragma unroll
  for (int it = 0; it < 4; it++){
    int l = (tid >> 4) + it * 16;
    int gl = l0 + l;
    const u16* rowp = xnb + ((size_t)b * L + gl) * 128 + d8s * 8;
    uint4 uc = *(const uint4*)rowp;
    uint4 um = (gl > 0)     ? *(const uint4*)(rowp - 128) : make_uint4(0, 0, 0, 0);
    uint4 up = (gl < L - 1) ? *(const uint4*)(rowp + 128) : make_uint4(0, 0, 0, 0);
    u16 em[8], ec[8], ep[8];
    __builtin_memcpy(em, &um, 16); __builtin_memcpy(ec, &uc, 16); __builtin_memcpy(ep, &up, 16);
    float fv[8];
    #pragma unroll
    for (int jj = 0; jj < 8; jj++)
      fv[jj] = cf[jj].x * b2f(em[jj]) + cf[jj].y * b2f(ec[jj]) + cf[jj].z * b2f(ep[jj]) + cf[jj].w;
    *(uint2*)&y_s8[l * 136 + d8s * 8] = pack_fp8x8(fv);
  }
  __syncthreads();
  long afq[4];
  #pragma unroll
  for (int dc = 0; dc < 4; dc++)
    afq[dc] = *(const long*)&y_s8[(wv * 16 + nn) * 136 + ((dc << 2) + quad) * 8];

  for (int h = 0; h < 8; h++){
    if (h) __syncthreads();   // st8 readers done -> w_s8 free
    const u8* src = wpk8 + ((size_t)(p * 8 + h) << 14);
    #pragma unroll
    for (int it = 0; it < 4; it++){
      int idx = (tid + 256 * it) << 4;
      *(uint4*)&w_s8[idx] = *(const uint4*)&src[idx];
    }
    __syncthreads();
    f32x4 acc[8];
    #pragma unroll
    for (int os = 0; os < 8; os++) acc[os] = (f32x4){0.f, 0.f, 0.f, 0.f};
    #pragma unroll
    for (int os = 0; os < 8; os++){
      #pragma unroll
      for (int dc = 0; dc < 4; dc++){
        int d8 = (dc << 2) + quad;
        long bf8 = *(const long*)&w_s8[foff(os, d8, nn)];
        acc[os] = __builtin_amdgcn_mfma_f32_16x16x32_fp8_fp8(afq[dc], bf8, acc[os], 0, 0, 0);
      }
    }
    #pragma unroll
    for (int os = 0; os < 8; os++)
      #pragma unroll
      for (int r = 0; r < 4; r++) acc[os][r] *= 0.0625f;
    if (p == 1){
      #pragma unroll
      for (int r = 0; r < 4; r++){
        float m = acc[0][r];
        #pragma unroll
        for (int os = 1; os < 8; os++) m = fmaxf(m, acc[os][r]);
        m = fmaxf(m, __shfl_xor(m, 1));
        m = fmaxf(m, __shfl_xor(m, 2));
        m = fmaxf(m, __shfl_xor(m, 4));
        m = fmaxf(m, __shfl_xor(m, 8));
        float s = 0.f;
        #pragma unroll
        for (int os = 0; os < 8; os++){ acc[os][r] = __expf(acc[os][r] - m); s += acc[os][r]; }
        s += __shfl_xor(s, 1);
        s += __shfl_xor(s, 2);
        s += __shfl_xor(s, 4);
        s += __shfl_xor(s, 8);
        float inv = 16.f / s;   // x16 fp8 k-scale folded in
        #pragma unroll
        for (int os = 0; os < 8; os++) acc[os][r] *= inv;
      }
    }
    __syncthreads();   // w_s8 MFMA reads done -> reuse as st8
    u8* st8 = w_s8;
    if (p == 2){
      #pragma unroll
      for (int os = 0; os < 8; os++){
        int e = (os << 4) + nn;
        #pragma unroll
        for (int r = 0; r < 4; r++)
          st8[faddr(wv * 16 + quad * 4 + r, e)] = f2e(acc[os][r]);
      }
    } else {
      #pragma unroll
      for (int os = 0; os < 8; os++){
        int e = (os << 4) + nn;
        #pragma unroll
        for (int r = 0; r < 4; r++)
          st8[(wv * 16 + quad * 4 + r) * 136 + e] = f2e(acc[os][r]);
      }
    }
    __syncthreads();
    if (p == 2){
      u8* v8 = args.outp[2];
      size_t tbase = ((size_t)((b * 8 + h) * 64 + lb)) << 13;
      #pragma unroll
      for (int it = 0; it < 2; it++){
        int idx = (tid + 256 * it) << 4;
        *(uint4*)&v8[tbase + idx] = *(const uint4*)&st8[idx];
      }
    } else {
      u8* outp8 = args.outp[p];
      size_t gbase = ((size_t)(b * 8 + h) * L + l0) * 128;
      #pragma unroll
      for (int it = 0; it < 4; it++){
        int item = tid + 256 * it;
        int row = item >> 4, d8 = item & 15;
        *(uint2*)&outp8[gbase + (size_t)row * 128 + d8 * 8] =
            *(const uint2*)&st8[row * 136 + d8 * 8];
      }
    }
  }
}

// ---------------------------------------------------------------- kk partials via fp8 MFMA with in-register byte transpose
__global__ __launch_bounds__(256, 3) void kk_kernel(
    const u8* __restrict__ qt8, const u8* __restrict__ kt8,
    float* __restrict__ kkp)
{
  __shared__ u8 qT8[16384];
  __shared__ u8 kT8[16384];
  const int tid = threadIdx.x;
  const int sp = blockIdx.x;   // 0..3
  const int n  = blockIdx.y;   // 0..63
  const int d8 = tid & 15;
  const int x8 = tid >> 4;
  const int lane = tid & 63, wv = tid >> 6;
  const int nn = lane & 15, quad = lane >> 4;
  const int m4 = (wv >> 1) << 2;
  const int e4 = (wv & 1) << 2;
  const size_t gbase = ((size_t)n * L + sp * 1024) * 128;

  uint2 rq[8], rk[8];
  #pragma unroll
  for (int j = 0; j < 8; j++){
    size_t off = gbase + (size_t)(x8 * 8 + j) * 128 + d8 * 8;
    rq[j] = *(const uint2*)&qt8[off];
    rk[j] = *(const uint2*)&kt8[off];
  }

  f32x4 acc[4][4];
  #pragma unroll
  for (int mi = 0; mi < 4; mi++)
    #pragma unroll
    for (int ei = 0; ei < 4; ei++) acc[mi][ei] = (f32x4){0.f, 0.f, 0.f, 0.f};

  for (int c = 0; c < 8; c++){
    #pragma unroll
    for (int i = 0; i < 8; i++){
      u8 cq[8], ck[8];
      #pragma unroll
      for (int j = 0; j < 8; j++){
        u8 tmp[8];
        __builtin_memcpy(tmp, &rq[j], 8); cq[j] = tmp[i];
        __builtin_memcpy(tmp, &rk[j], 8); ck[j] = tmp[i];
      }
      int d = d8 * 8 + i;
      int off = t8off(d >> 4, d & 15, x8);
      uint2 uq, uk;
      __builtin_memcpy(&uq, cq, 8); __builtin_memcpy(&uk, ck, 8);
      *(uint2*)&qT8[off] = uq;
      *(uint2*)&kT8[off] = uk;
    }
    __syncthreads();
    if (c < 7){
      #pragma unroll
      for (int j = 0; j < 8; j++){
        size_t off = gbase + (size_t)((c + 1) * 128 + x8 * 8 + j) * 128 + d8 * 8;
        rq[j] = *(const uint2*)&qt8[off];
        rk[j] = *(const uint2*)&kt8[off];
      }
    }
    #pragma unroll
    for (int ks = 0; ks < 4; ks++){
      int x8f = (ks << 2) + quad;
      long af[4], bf[4];
      #pragma unroll
      for (int t = 0; t < 4; t++){
        af[t] = *(const long*)&qT8[t8off(m4 + t, nn, x8f)];
        bf[t] = *(const long*)&kT8[t8off(e4 + t, nn, x8f)];
      }
      #pragma unroll
      for (int mi = 0; mi < 4; mi++)
        #pragma unroll
        for (int ei = 0; ei < 4; ei++)
          acc[mi][ei] = __builtin_amdgcn_mfma_f32_16x16x32_fp8_fp8(af[mi], bf[ei], acc[mi][ei], 0, 0, 0);
    }
    __syncthreads();
  }

  float* op = kkp + ((size_t)(sp * 64 + n) << 14);
  #pragma unroll
  for (int mi = 0; mi < 4; mi++){
    #pragma unroll
    for (int r = 0; r < 4; r++){
      int d = (m4 << 4) + mi * 16 + quad * 4 + r;
      #pragma unroll
      for (int ei = 0; ei < 4; ei++)
        op[d * 128 + (e4 << 4) + ei * 16 + nn] = acc[mi][ei][r];
    }
  }
}

// ---------------------------------------------------------------- kk reduce + scale + pack to fp8 B tiles
__global__ __launch_bounds__(256) void kkred_kernel(
    const float* __restrict__ kkp, u8* __restrict__ kkbb8)
{
  int item = blockIdx.x * 256 + threadIdx.x;
  int nn = item & 15, d8 = (item >> 4) & 15, os = (item >> 8) & 7, n = item >> 11;
  int e = os * 16 + nn;
  float fv[8];
  #pragma unroll
  for (int j = 0; j < 8; j++){
    float s = 0.f;
    #pragma unroll
    for (int sp = 0; sp < 4; sp++)
      s += kkp[(size_t)sp * (64 * 16384) + n * 16384 + (d8 * 8 + j) * 128 + e];
    fv[j] = s * (SCALEF * 2.f);
  }
  *(uint2*)&kkbb8[((size_t)n << 14) + foff(os, d8, nn)] = pack_fp8x8(fv);
}

// ---------------------------------------------------------------- gateout: all-fp8 MFMA -> outt fp8 frag-major
__global__ __launch_bounds__(256, 4) void gateout_kernel(
    const u8* __restrict__ qt8, const u8* __restrict__ vt8,
    const u8* __restrict__ kkbb8, const u8* __restrict__ w2tb8,
    const float* __restrict__ c2, u8* __restrict__ outt8)
{
  __shared__ __attribute__((aligned(16))) u8 q_s8[64 * 144];  // fp8 q; reused as st8
  __shared__ __attribute__((aligned(16))) u8 v_s8[8192];
  const int tid = threadIdx.x;
  const int lb = blockIdx.x;   // 0..63
  const int n  = blockIdx.y;   // 0..63
  const int l0 = lb * 64;
  const int lane = tid & 63, wv = tid >> 6;
  const int nn = lane & 15, quad = lane >> 4;
  const size_t vtile = ((size_t)(n * 64 + lb)) << 13;
  const size_t qbase = ((size_t)n * L + l0) * 128;

  #pragma unroll
  for (int it = 0; it < 4; it++){
    int item = tid + 256 * it;               // 1024 items x 8B
    int d8b = item & 15, l = item >> 4;
    *(uint2*)&q_s8[l * 144 + d8b * 8] = *(const uint2*)&qt8[qbase + (size_t)l * 128 + d8b * 8];
  }
  #pragma unroll
  for (int it = 0; it < 2; it++){
    int idx = (tid + 256 * it) << 4;
    *(uint4*)&v_s8[idx] = *(const uint4*)&vt8[vtile + idx];
  }
  __syncthreads();

  long aq[4], av[4];
  #pragma unroll
  for (int dc = 0; dc < 4; dc++){
    aq[dc] = *(const long*)&q_s8[(wv * 16 + nn) * 144 + ((dc << 2) + quad) * 8];
    av[dc] = *(const long*)&v_s8[foff(wv, (dc << 2) + quad, nn)];
  }
  const u8* kb8 = kkbb8 + ((size_t)n << 14);
  f32x4 acc_o[8], acc_g[8];
  #pragma unroll
  for (int os = 0; os < 8; os++){ acc_o[os] = (f32x4){0,0,0,0}; acc_g[os] = (f32x4){0,0,0,0}; }
  #pragma unroll
  for (int os = 0; os < 8; os++){
    #pragma unroll
    for (int dc = 0; dc < 4; dc++){
      int d8 = (dc << 2) + quad;
      long bkk = *(const long*)&kb8[foff(os, d8, nn)];
      long bw8 = *(const long*)&w2tb8[foff(os, d8, nn)];
      acc_o[os] = __builtin_amdgcn_mfma_f32_16x16x32_fp8_fp8(av[dc], bkk, acc_o[os], 0, 0, 0);
      acc_g[os] = __builtin_amdgcn_mfma_f32_16x16x32_fp8_fp8(aq[dc], bw8, acc_g[os], 0, 0, 0);
    }
  }
  __syncthreads();   // q_s8 reads done -> reuse as st8
  u8* st8 = q_s8;
  #pragma unroll
  for (int os = 0; os < 8; os++){
    int e = (os << 4) + nn;
    float c2v = c2[e];
    #pragma unroll
    for (int r = 0; r < 4; r++){
      int xr = wv * 16 + quad * 4 + r;
      float ve = e2f(v_s8[faddr(xr, e)]);
      float val = acc_o[os][r] * (1.f / 32.f) + sigmoidf(acc_g[os][r] * 0.0625f + c2v) * ve;
      st8[faddr(xr, e)] = f2e(val);
    }
  }
  __syncthreads();
  #pragma unroll
  for (int it = 0; it < 2; it++){
    int idx = (tid + 256 * it) << 4;
    *(uint4*)&outt8[vtile + idx] = *(const uint4*)&st8[idx];
  }
}

// ---------------------------------------------------------------- attn_ff: outw fp8 MFMA + bias + residual (LDS) + LN2 + ff1 fp8 + gelu + ff2 bf16 + residual -> out
__global__ __launch_bounds__(256, 3) void attn_ff_kernel(
    const u8* __restrict__ outt8, const u8* __restrict__ wpk8,
    const u16* __restrict__ wpk,
    const float* __restrict__ out_b, const float* __restrict__ x,
    const float* __restrict__ g2, const float* __restrict__ bt2,
    const float* __restrict__ b1, const float* __restrict__ b2,
    float* __restrict__ outp)
{
  __shared__ float stf[128 * 68];                         // x2 tile [o][l], live to the end
  __shared__ __attribute__((aligned(16))) u16 hs_u[64 * 136];  // union: a_s8 fp8 / h_s bf16 / stf2 f32
  u8* a_s8 = (u8*)hs_u;
  u16* h_s = hs_u;
  float* stf2 = (float*)hs_u;
  const int tid = threadIdx.x;
  const int lb = blockIdx.x;   // 64
  const int b  = blockIdx.y;   // 8
  const int l0 = lb * 64;
  const int lane = tid & 63, wv = tid >> 6;
  const int nn = lane & 15, quad = lane >> 4;

  // ---- phase 1: out_w fp8 MFMA over 8 heads (A,B direct from L2) ----
  {
    f32x4 acc[8];
    #pragma unroll
    for (int os = 0; os < 8; os++) acc[os] = (f32x4){0,0,0,0};
    const u8* wpk8o = wpk8 + ((size_t)24 << 14);
    for (int h = 0; h < 8; h++){
      const size_t tbase = ((size_t)((b * 8 + h) * 64 + lb)) << 13;
      long af[4];
      #pragma unroll
      for (int dc = 0; dc < 4; dc++)
        af[dc] = *(const long*)&outt8[tbase + foff(wv, (dc << 2) + quad, nn)];
      const u8* bp8 = wpk8o + (h << 14);
      #pragma unroll
      for (int os = 0; os < 8; os++){
        #pragma unroll
        for (int dc = 0; dc < 4; dc++){
          long bf8 = *(const long*)&bp8[foff(os, (dc << 2) + quad, nn)];
          acc[os] = __builtin_amdgcn_mfma_f32_16x16x32_fp8_fp8(af[dc], bf8, acc[os], 0, 0, 0);
        }
      }
    }
    #pragma unroll
    for (int os = 0; os < 8; os++)
      #pragma unroll
      for (int r = 0; r < 4; r++)
        stf[((os << 4) + nn) * 68 + wv * 16 + quad * 4 + r] = acc[os][r] * 0.0625f;
  }
  __syncthreads();
  // ---- phase 2: bias + residual x, keep x2 in stf (no global write) ----
  {
    int o = tid >> 1, lh = tid & 1;
    float bias = out_b[o];
    size_t gbase = ((size_t)b * 128 + o) * L + l0 + lh * 32;
    float* sp = &stf[o * 68 + lh * 32];
    #pragma unroll
    for (int k = 0; k < 8; k++){
      float4 xv = *(const float4*)&x[gbase + k * 4];
      float4 sv = *(float4*)&sp[k * 4];
      *(float4*)&sp[k * 4] = make_float4(sv.x + bias + xv.x, sv.y + bias + xv.y,
                                         sv.z + bias + xv.z, sv.w + bias + xv.w);
    }
  }
  __syncthreads();
  // ---- phase 3: LN2 per position -> fp8 a_s8 [l][136] ----
  {
    int l = tid >> 2, part = tid & 3;
    float vv[32];
    float s = 0.f, ss = 0.f;
    #pragma unroll
    for (int i = 0; i < 32; i++){
      float v = stf[(part * 32 + i) * 68 + l];
      vv[i] = v; s += v; ss += v * v;
    }
    s += __shfl_xor(s, 1);  s += __shfl_xor(s, 2);
    ss += __shfl_xor(ss, 1); ss += __shfl_xor(ss, 2);
    float m = s * (1.f / 128.f);
    float rs = rsqrtf(ss * (1.f / 128.f) - m * m + EPS);
    #pragma unroll
    for (int c = 0; c < 4; c++){
      float fv[8];
      #pragma unroll
      for (int j = 0; j < 8; j++){
        int d = part * 32 + c * 8 + j;
        fv[j] = (vv[c * 8 + j] - m) * rs * g2[d] + bt2[d];
      }
      *(uint2*)&a_s8[l * 136 + part * 32 + c * 8] = pack_fp8x8(fv);
    }
  }
  __syncthreads();
  // ---- phase 4: ff1 fp8 + gelu + ff2 bf16 ----
  long af8[4];
  #pragma unroll
  for (int dc = 0; dc < 4; dc++)
    af8[dc] = *(const long*)&a_s8[(wv * 16 + nn) * 136 + ((dc << 2) + quad) * 8];

  f32x4 acc_out[8];
  #pragma unroll
  for (int os = 0; os < 8; os++) acc_out[os] = (f32x4){0.f, 0.f, 0.f, 0.f};

  for (int fc = 0; fc < 4; fc++){
    const u8* bp1 = wpk8 + (size_t)(32 + fc) * 16384;
    f32x4 hacc[8];
    #pragma unroll
    for (int os = 0; os < 8; os++) hacc[os] = (f32x4){0.f, 0.f, 0.f, 0.f};
    #pragma unroll
    for (int os = 0; os < 8; os++){
      #pragma unroll
      for (int dc = 0; dc < 4; dc++){
        long bf8 = *(const long*)&bp1[foff(os, (dc << 2) + quad, nn)];
        hacc[os] = __builtin_amdgcn_mfma_f32_16x16x32_fp8_fp8(af8[dc], bf8, hacc[os], 0, 0, 0);
      }
    }
    __syncthreads();   // h_s free (af8 loads done / prev hf readers done)
    #pragma unroll
    for (int os = 0; os < 8; os++){
      float bias = b1[fc * 128 + (os << 4) + nn];
      #pragma unroll
      for (int r = 0; r < 4; r++){
        float v = hacc[os][r] * 0.0625f + bias;
        float ge = 0.5f * v * (1.f + erff(v * 0.70710678118654752f));
        h_s[(wv * 16 + quad * 4 + r) * 136 + (os << 4) + nn] = f2b(ge);
      }
    }
    __syncthreads();
    bf16x8 hf[4];
    #pragma unroll
    for (int dc = 0; dc < 4; dc++)
      hf[dc] = *(const bf16x8*)&h_s[(wv * 16 + nn) * 136 + ((dc << 2) + quad) * 8];
    const u16* bp2 = wpk + (size_t)(36 + fc) * 16384;
    #pragma unroll
    for (int os = 0; os < 8; os++){
      #pragma unroll
      for (int dc = 0; dc < 4; dc++){
        int d8 = (dc << 2) + quad;
        bf16x8 bf = *(const bf16x8*)&bp2[(os << 11) + (d8 << 7) + ((nn ^ d8) << 3)];
        acc_out[os] = __builtin_amdgcn_mfma_f32_16x16x32_bf16(hf[dc], bf, acc_out[os], 0, 0, 0);
      }
    }
  }

  // ---- phase 5: epilogue, residual from stf (LDS), write out ----
  #pragma unroll
  for (int t = 0; t < 2; t++){
    __syncthreads();
    #pragma unroll
    for (int osl = 0; osl < 4; osl++){
      int os = t * 4 + osl;
      #pragma unroll
      for (int r = 0; r < 4; r++)
        stf2[((osl << 4) + nn) * 68 + wv * 16 + quad * 4 + r] = acc_out[os][r];
    }
    __syncthreads();
    int ol = tid >> 2;
    int o  = t * 64 + ol;
    int lc = (tid & 3) * 16;
    float bias = b2[o];
    size_t gbase = ((size_t)b * 128 + o) * L + l0 + lc;
    #pragma unroll
    for (int k = 0; k < 4; k++){
      float4 sv = *(const float4*)&stf2[ol * 68 + lc + k * 4];
      float4 xv = *(const float4*)&stf[o * 68 + lc + k * 4];
      *(float4*)&outp[gbase + k * 4] = make_float4(sv.x + bias + xv.x, sv.y + bias + xv.y,
                                                   sv.z + bias + xv.z, sv.w + bias + xv.w);
    }
  }
}

} // namespace

extern "C" void kernel_launch(void* const* d_in, const int* in_sizes, int n_in,
                              void* d_out, int out_size, void* d_ws, size_t ws_size,
                              hipStream_t stream)
{
  const float* x      = (const float*)d_in[0];
  const float* ln1_g  = (const float*)d_in[1];
  const float* ln1_b  = (const float*)d_in[2];
  const float* q_dw   = (const float*)d_in[3];
  const float* q_bng  = (const float*)d_in[4];
  const float* q_bnb  = (const float*)d_in[5];
  const float* q_bnm  = (const float*)d_in[6];
  const float* q_bnv  = (const float*)d_in[7];
  const float* q_pw   = (const float*)d_in[8];
  const float* k_dw   = (const float*)d_in[9];
  const float* k_bng  = (const float*)d_in[10];
  const float* k_bnb  = (const float*)d_in[11];
  const float* k_bnm  = (const float*)d_in[12];
  const float* k_bnv  = (const float*)d_in[13];
  const float* k_pw   = (const float*)d_in[14];
  const float* v_dw   = (const float*)d_in[15];
  const float* v_bng  = (const float*)d_in[16];
  const float* v_bnb  = (const float*)d_in[17];
  const float* v_bnm  = (const float*)d_in[18];
  const float* v_bnv  = (const float*)d_in[19];
  const float* v_pw   = (const float*)d_in[20];
  const float* dwc_dw  = (const float*)d_in[21];
  const float* dwc_bng = (const float*)d_in[22];
  const float* dwc_bnb = (const float*)d_in[23];
  const float* dwc_bnm = (const float*)d_in[24];
  const float* dwc_bnv = (const float*)d_in[25];
  const float* dwc_pw  = (const float*)d_in[26];
  const float* out_w  = (const float*)d_in[27];
  const float* out_b  = (const float*)d_in[28];
  const float* ln2_g  = (const float*)d_in[29];
  const float* ln2_b  = (const float*)d_in[30];
  const float* ff_w1  = (const float*)d_in[31];
  const float* ff_b1  = (const float*)d_in[32];
  const float* ff_w2  = (const float*)d_in[33];
  const float* ff_b2  = (const float*)d_in[34];
  float* out = (float*)d_out;

  // ---- workspace layout (lifetime-aliased) ----
  // [0,32M)    qt8 fp8            (qkv .. gateout)
  // [32,64M)   kt8 fp8            (qkv .. kk)
  // [64,96M)   outt8 fp8          (gateout .. attn_ff)
  // [128,160M) vt8 fp8            (qkv .. gateout)
  // [192,200M) xnb bf16 (prep..qkv) -> kkbb8 1MB (kkred..gateout)
  // [200,216M) kkp 16MB (kk..kkred)
  // [216M..)   c2 + wpk bf16 (ff_w2 tiles); wpk8 fp8 37 tiles @218M
  char* w = (char*)d_ws;
  u8*   qt8   = (u8*)(w);
  u8*   kt8   = (u8*)(w + (32ull  << 20));
  u8*   outt8 = (u8*)(w + (64ull  << 20));
  u8*   vt8   = (u8*)(w + (128ull << 20));
  u16*  xnb   = (u16*)(w + (192ull << 20));
  u8*   kkbb8 = (u8*)(w + (192ull << 20));
  float* kkp  = (float*)(w + (200ull << 20));
  float* c2   = (float*)(w + (216ull << 20));
  u16*  wpk   = (u16*)(w + (216ull << 20) + 65536);
  u8*   wpk8  = (u8*)(w + (218ull << 20));
  u8*   w2tb8 = wpk8 + ((size_t)36 << 14);   // gate pw tile

  prep_kernel<<<582, 256, 0, stream>>>(x, ln1_g, ln1_b, xnb,
                                       q_pw, k_pw, v_pw, out_w, ff_w1, ff_w2,
                                       dwc_dw, dwc_bng, dwc_bnv, dwc_bnb, dwc_bnm, dwc_pw,
                                       wpk, c2, wpk8);

  QkvArgs qa;
  qa.dw[0] = q_dw;  qa.bng[0] = q_bng; qa.bnb[0] = q_bnb; qa.bnm[0] = q_bnm; qa.bnv[0] = q_bnv; qa.outp[0] = qt8;
  qa.dw[1] = k_dw;  qa.bng[1] = k_bng; qa.bnb[1] = k_bnb; qa.bnm[1] = k_bnm; qa.bnv[1] = k_bnv; qa.outp[1] = kt8;
  qa.dw[2] = v_dw;  qa.bng[2] = v_bng; qa.bnb[2] = v_bnb; qa.bnm[2] = v_bnm; qa.bnv[2] = v_bnv; qa.outp[2] = vt8;
  qkv_fused_kernel<<<dim3(64, 24), 256, 0, stream>>>(xnb, wpk8, qa);

  kk_kernel<<<dim3(4, 64), 256, 0, stream>>>(qt8, kt8, kkp);
  kkred_kernel<<<512, 256, 0, stream>>>(kkp, kkbb8);
  gateout_kernel<<<dim3(64, 64), 256, 0, stream>>>(qt8, vt8, kkbb8, w2tb8, c2, outt8);
  attn_ff_kernel<<<dim3(64, 8), 256, 0, stream>>>(outt8, wpk8, wpk, out_b, x,
                                                  ln2_g, ln2_b, ff_b1, ff_b2, out);
}

// Round 17
// 347.423 us; speedup vs baseline: 1.2081x; 1.2081x over previous
//
#include <hip/hip_runtime.h>
#include <hip/hip_bf16.h>
#include <math.h>

#define DI __device__ __forceinline__

namespace {

constexpr int L = 4096;
constexpr float EPS = 1e-5f;
constexpr float SCALEF = 0.08838834764831845f;  // 128^-0.5

typedef unsigned short u16;
typedef unsigned int u32;
typedef unsigned char u8;
typedef __attribute__((ext_vector_type(8))) short bf16x8;
typedef __attribute__((ext_vector_type(4))) float f32x4;

DI float b2f(u16 h){ u32 u = ((u32)h) << 16; float f; __builtin_memcpy(&f, &u, 4); return f; }
DI u16 f2b(float f){ u32 u; __builtin_memcpy(&u, &f, 4); u32 r = u + 0x7fffu + ((u >> 16) & 1u); return (u16)(r >> 16); }
DI float sigmoidf(float x){ return 1.f / (1.f + __expf(-x)); }

DI uint2 pack_fp8x8(const float* v){
  u32 lo = __builtin_amdgcn_cvt_pk_fp8_f32(v[0], v[1], 0, false);
  lo = (u32)__builtin_amdgcn_cvt_pk_fp8_f32(v[2], v[3], lo, true);
  u32 hi = __builtin_amdgcn_cvt_pk_fp8_f32(v[4], v[5], 0, false);
  hi = (u32)__builtin_amdgcn_cvt_pk_fp8_f32(v[6], v[7], hi, true);
  return make_uint2(lo, hi);
}
DI u8 f2e(float v){ return (u8)__builtin_amdgcn_cvt_pk_fp8_f32(v, v, 0, false); }
DI float e2f(u8 c){ return __builtin_amdgcn_cvt_f32_fp8((int)c, 0); }

// bf16 B-frag packed tile offset (o = output col, d8 = k-chunk), u16 units
DI int boff(int o, int d8){ return ((o >> 4) << 11) + (d8 << 7) + (((o & 15) ^ d8) << 3); }
// fp8 frag-major offset (A tiles 64x128: g=x>>4; B tiles 128x128: g=o>>4), bytes
DI int foff(int g, int k8, int nn){ return (g << 11) + (k8 << 7) + (nn << 3); }
// fp8 A-tile element address (x 0..63, e 0..127), bytes
DI int faddr(int x, int e){ return ((x >> 4) << 11) + ((e >> 3) << 7) + ((x & 15) << 3) + (e & 7); }
// fp8 transposed [d][x] tile offset (dhi=d>>4, nl=d&15, x8=x>>3), bytes
DI int t8off(int dhi, int nl, int x8){ return (dhi << 11) + (x8 << 7) + (((nl ^ x8 ^ dhi) & 15) << 3); }

// ---------------------------------------------------------------- prep: LN1 (blocks 0-511) + weight pack (blocks 512-581)
__global__ __launch_bounds__(256) void prep_kernel(
    const float* __restrict__ x, const float* __restrict__ ln1_g,
    const float* __restrict__ ln1_b, u16* __restrict__ xnb,
    const float* __restrict__ q_pw, const float* __restrict__ k_pw,
    const float* __restrict__ v_pw, const float* __restrict__ out_w,
    const float* __restrict__ ff_w1, const float* __restrict__ ff_w2,
    const float* __restrict__ dwc_dw, const float* __restrict__ dwc_bng,
    const float* __restrict__ dwc_bnv, const float* __restrict__ dwc_bnb,
    const float* __restrict__ dwc_bnm, const float* __restrict__ dwc_pw,
    u16* __restrict__ wpk, float* __restrict__ c2, u8* __restrict__ wpk8)
{
  const int tid = threadIdx.x;
  if (blockIdx.x < 512){
    const int pos = blockIdx.x * 64 + (tid >> 2);
    const int part = tid & 3;
    const int b = pos >> 12, l = pos & (L - 1);
    const float* xb = x + (size_t)b * 128 * L + l;
    float vv[32];
    float s = 0.f, ss = 0.f;
    #pragma unroll
    for (int i = 0; i < 32; i++){
      float v = xb[(size_t)(part * 32 + i) * L];
      vv[i] = v; s += v; ss += v * v;
    }
    s += __shfl_xor(s, 1);  s += __shfl_xor(s, 2);
    ss += __shfl_xor(ss, 1); ss += __shfl_xor(ss, 2);
    const float m = s * (1.f / 128.f);
    const float rs = rsqrtf(ss * (1.f / 128.f) - m * m + EPS);
    #pragma unroll
    for (int c = 0; c < 4; c++){
      u16 pk[8];
      #pragma unroll
      for (int j = 0; j < 8; j++){
        int d = part * 32 + c * 8 + j;
        pk[j] = f2b((vv[c * 8 + j] - m) * rs * ln1_g[d] + ln1_b[d]);
      }
      uint4 uu; __builtin_memcpy(&uu, pk, 16);
      *(uint4*)&xnb[(size_t)pos * 128 + part * 32 + c * 8] = uu;
    }
    return;
  }
  const int blk = blockIdx.x - 512;
  if (blk < 37){
    int t8 = blk;
    #pragma unroll
    for (int it = 0; it < 8; it++){
      int item = tid + 256 * it;   // 2048: os(8)*256 + k8(16)*16 + nn(16)
      int nn = item & 15, k8 = (item >> 4) & 15, os = item >> 8;
      int o = os * 16 + nn;
      float fv[8];
      if (t8 < 24){
        int p = t8 >> 3, h = t8 & 7;
        const float* pw = (p == 0) ? q_pw : (p == 1 ? k_pw : v_pw);
        #pragma unroll
        for (int j = 0; j < 8; j++)
          fv[j] = pw[(size_t)(h * 128 + o) * 128 + k8 * 8 + j] * 16.f;
      } else if (t8 < 32){
        #pragma unroll
        for (int j = 0; j < 8; j++)
          fv[j] = out_w[(size_t)o * 1024 + (t8 - 24) * 128 + k8 * 8 + j] * 16.f;
      } else if (t8 < 36){
        #pragma unroll
        for (int j = 0; j < 8; j++)
          fv[j] = ff_w1[(size_t)((t8 - 32) * 128 + o) * 128 + k8 * 8 + j] * 16.f;
      } else {
        #pragma unroll
        for (int j = 0; j < 8; j++){
          int d = k8 * 8 + j;
          float sD = dwc_bng[d] * rsqrtf(dwc_bnv[d] + EPS);
          fv[j] = dwc_pw[(size_t)o * 128 + d] * dwc_dw[d] * sD * 16.f;
        }
      }
      *(uint2*)&wpk8[(size_t)t8 * 16384 + foff(os, k8, nn)] = pack_fp8x8(fv);
    }
  } else if (blk < 69){
    int vitem = (blk - 37) * 256 + tid;   // 8192 over 4 tiles
    int d8 = vitem & 15;
    int o  = (vitem >> 4) & 127;
    int t  = 36 + (vitem >> 11);
    const float* src = ff_w2 + (size_t)o * 512 + (t - 36) * 128 + d8 * 8;
    u16 pk[8];
    #pragma unroll
    for (int j = 0; j < 8; j++) pk[j] = f2b(src[j]);
    uint4 uu; __builtin_memcpy(&uu, pk, 16);
    *(uint4*)&wpk[(size_t)t * 16384 + boff(o, d8)] = uu;
  } else {
    int e = tid;
    if (e < 128){
      float cacc = 0.f;
      for (int d = 0; d < 128; d++){
        float sD = dwc_bng[d] * rsqrtf(dwc_bnv[d] + EPS);
        cacc += dwc_pw[(size_t)e * 128 + d] * (dwc_bnb[d] - dwc_bnm[d] * sD);
      }
      c2[e] = cacc;
    }
  }
}

// ---------------------------------------------------------------- fused qkv: dwconv+BN -> fp8 MFMA -> (softmax k) -> direct fp8 epilogue
struct QkvArgs {
  const float* dw[3];
  const float* bng[3];
  const float* bnb[3];
  const float* bnm[3];
  const float* bnv[3];
  u8* outp[3];
};

__global__ __launch_bounds__(256, 5) void qkv_fused_kernel(
    const u16* __restrict__ xnb, const u8* __restrict__ wpk8, QkvArgs args)
{
  __shared__ __attribute__((aligned(16))) u8 y_s8[64 * 136];   // fp8 A tile
  __shared__ __attribute__((aligned(16))) u8 w_s8[16384];      // fp8 B tile; aliased as st8
  __shared__ float4 coef[128];
  const int tid = threadIdx.x;
  const int lb = blockIdx.x;   // 0..63
  const int bz = blockIdx.y;   // 0..23
  const int b  = bz / 3;
  const int p  = bz % 3;
  const int l0 = lb * 64;
  const int lane = tid & 63, wv = tid >> 6;
  const int nn = lane & 15, quad = lane >> 4;
  const int d8s = tid & 15;

  if (tid < 128){
    int d = tid;
    float sD = args.bng[p][d] * rsqrtf(args.bnv[p][d] + EPS);
    const float* dw = args.dw[p];
    coef[d] = make_float4(dw[d * 3] * sD, dw[d * 3 + 1] * sD, dw[d * 3 + 2] * sD,
                          args.bnb[p][d] - args.bnm[p][d] * sD);
  }
  __syncthreads();
  float4 cf[8];
  #pragma unroll
  for (int jj = 0; jj < 8; jj++) cf[jj] = coef[d8s * 8 + jj];
  #pragma unroll
  for (int it = 0; it < 4; it++){
    int l = (tid >> 4) + it * 16;
    int gl = l0 + l;
    const u16* rowp = xnb + ((size_t)b * L + gl) * 128 + d8s * 8;
    uint4 uc = *(const uint4*)rowp;
    uint4 um = (gl > 0)     ? *(const uint4*)(rowp - 128) : make_uint4(0, 0, 0, 0);
    uint4 up = (gl < L - 1) ? *(const uint4*)(rowp + 128) : make_uint4(0, 0, 0, 0);
    u16 em[8], ec[8], ep[8];
    __builtin_memcpy(em, &um, 16); __builtin_memcpy(ec, &uc, 16); __builtin_memcpy(ep, &up, 16);
    float fv[8];
    #pragma unroll
    for (int jj = 0; jj < 8; jj++)
      fv[jj] = cf[jj].x * b2f(em[jj]) + cf[jj].y * b2f(ec[jj]) + cf[jj].z * b2f(ep[jj]) + cf[jj].w;
    *(uint2*)&y_s8[l * 136 + d8s * 8] = pack_fp8x8(fv);
  }
  __syncthreads();
  long afq[4];
  #pragma unroll
  for (int dc = 0; dc < 4; dc++)
    afq[dc] = *(const long*)&y_s8[(wv * 16 + nn) * 136 + ((dc << 2) + quad) * 8];

  for (int h = 0; h < 8; h++){
    if (h) __syncthreads();   // st8 readers done -> w_s8 free
    const u8* src = wpk8 + ((size_t)(p * 8 + h) << 14);
    #pragma unroll
    for (int it = 0; it < 4; it++){
      int idx = (tid + 256 * it) << 4;
      *(uint4*)&w_s8[idx] = *(const uint4*)&src[idx];
    }
    __syncthreads();
    f32x4 acc[8];
    #pragma unroll
    for (int os = 0; os < 8; os++) acc[os] = (f32x4){0.f, 0.f, 0.f, 0.f};
    #pragma unroll
    for (int os = 0; os < 8; os++){
      #pragma unroll
      for (int dc = 0; dc < 4; dc++){
        int d8 = (dc << 2) + quad;
        long bf8 = *(const long*)&w_s8[foff(os, d8, nn)];
        acc[os] = __builtin_amdgcn_mfma_f32_16x16x32_fp8_fp8(afq[dc], bf8, acc[os], 0, 0, 0);
      }
    }
    #pragma unroll
    for (int os = 0; os < 8; os++)
      #pragma unroll
      for (int r = 0; r < 4; r++) acc[os][r] *= 0.0625f;
    if (p == 1){
      #pragma unroll
      for (int r = 0; r < 4; r++){
        float m = acc[0][r];
        #pragma unroll
        for (int os = 1; os < 8; os++) m = fmaxf(m, acc[os][r]);
        m = fmaxf(m, __shfl_xor(m, 1));
        m = fmaxf(m, __shfl_xor(m, 2));
        m = fmaxf(m, __shfl_xor(m, 4));
        m = fmaxf(m, __shfl_xor(m, 8));
        float s = 0.f;
        #pragma unroll
        for (int os = 0; os < 8; os++){ acc[os][r] = __expf(acc[os][r] - m); s += acc[os][r]; }
        s += __shfl_xor(s, 1);
        s += __shfl_xor(s, 2);
        s += __shfl_xor(s, 4);
        s += __shfl_xor(s, 8);
        float inv = 16.f / s;   // x16 fp8 k-scale folded in
        #pragma unroll
        for (int os = 0; os < 8; os++) acc[os][r] *= inv;
      }
    }
    __syncthreads();   // w_s8 MFMA reads done -> reuse as st8
    u8* st8 = w_s8;
    if (p == 2){
      #pragma unroll
      for (int os = 0; os < 8; os++){
        int e = (os << 4) + nn;
        #pragma unroll
        for (int r = 0; r < 4; r++)
          st8[faddr(wv * 16 + quad * 4 + r, e)] = f2e(acc[os][r]);
      }
    } else {
      #pragma unroll
      for (int os = 0; os < 8; os++){
        int e = (os << 4) + nn;
        #pragma unroll
        for (int r = 0; r < 4; r++)
          st8[(wv * 16 + quad * 4 + r) * 136 + e] = f2e(acc[os][r]);
      }
    }
    __syncthreads();
    if (p == 2){
      u8* v8 = args.outp[2];
      size_t tbase = ((size_t)((b * 8 + h) * 64 + lb)) << 13;
      #pragma unroll
      for (int it = 0; it < 2; it++){
        int idx = (tid + 256 * it) << 4;
        *(uint4*)&v8[tbase + idx] = *(const uint4*)&st8[idx];
      }
    } else {
      u8* outp8 = args.outp[p];
      size_t gbase = ((size_t)(b * 8 + h) * L + l0) * 128;
      #pragma unroll
      for (int it = 0; it < 4; it++){
        int item = tid + 256 * it;
        int row = item >> 4, d8 = item & 15;
        *(uint2*)&outp8[gbase + (size_t)row * 128 + d8 * 8] =
            *(const uint2*)&st8[row * 136 + d8 * 8];
      }
    }
  }
}

// ---------------------------------------------------------------- kk partials via fp8 MFMA with in-register byte transpose
__global__ __launch_bounds__(256, 3) void kk_kernel(
    const u8* __restrict__ qt8, const u8* __restrict__ kt8,
    float* __restrict__ kkp)
{
  __shared__ u8 qT8[16384];
  __shared__ u8 kT8[16384];
  const int tid = threadIdx.x;
  const int sp = blockIdx.x;   // 0..3
  const int n  = blockIdx.y;   // 0..63
  const int d8 = tid & 15;
  const int x8 = tid >> 4;
  const int lane = tid & 63, wv = tid >> 6;
  const int nn = lane & 15, quad = lane >> 4;
  const int m4 = (wv >> 1) << 2;
  const int e4 = (wv & 1) << 2;
  const size_t gbase = ((size_t)n * L + sp * 1024) * 128;

  uint2 rq[8], rk[8];
  #pragma unroll
  for (int j = 0; j < 8; j++){
    size_t off = gbase + (size_t)(x8 * 8 + j) * 128 + d8 * 8;
    rq[j] = *(const uint2*)&qt8[off];
    rk[j] = *(const uint2*)&kt8[off];
  }

  f32x4 acc[4][4];
  #pragma unroll
  for (int mi = 0; mi < 4; mi++)
    #pragma unroll
    for (int ei = 0; ei < 4; ei++) acc[mi][ei] = (f32x4){0.f, 0.f, 0.f, 0.f};

  for (int c = 0; c < 8; c++){
    #pragma unroll
    for (int i = 0; i < 8; i++){
      u8 cq[8], ck[8];
      #pragma unroll
      for (int j = 0; j < 8; j++){
        u8 tmp[8];
        __builtin_memcpy(tmp, &rq[j], 8); cq[j] = tmp[i];
        __builtin_memcpy(tmp, &rk[j], 8); ck[j] = tmp[i];
      }
      int d = d8 * 8 + i;
      int off = t8off(d >> 4, d & 15, x8);
      uint2 uq, uk;
      __builtin_memcpy(&uq, cq, 8); __builtin_memcpy(&uk, ck, 8);
      *(uint2*)&qT8[off] = uq;
      *(uint2*)&kT8[off] = uk;
    }
    __syncthreads();
    if (c < 7){
      #pragma unroll
      for (int j = 0; j < 8; j++){
        size_t off = gbase + (size_t)((c + 1) * 128 + x8 * 8 + j) * 128 + d8 * 8;
        rq[j] = *(const uint2*)&qt8[off];
        rk[j] = *(const uint2*)&kt8[off];
      }
    }
    #pragma unroll
    for (int ks = 0; ks < 4; ks++){
      int x8f = (ks << 2) + quad;
      long af[4], bf[4];
      #pragma unroll
      for (int t = 0; t < 4; t++){
        af[t] = *(const long*)&qT8[t8off(m4 + t, nn, x8f)];
        bf[t] = *(const long*)&kT8[t8off(e4 + t, nn, x8f)];
      }
      #pragma unroll
      for (int mi = 0; mi < 4; mi++)
        #pragma unroll
        for (int ei = 0; ei < 4; ei++)
          acc[mi][ei] = __builtin_amdgcn_mfma_f32_16x16x32_fp8_fp8(af[mi], bf[ei], acc[mi][ei], 0, 0, 0);
    }
    __syncthreads();
  }

  float* op = kkp + ((size_t)(sp * 64 + n) << 14);
  #pragma unroll
  for (int mi = 0; mi < 4; mi++){
    #pragma unroll
    for (int r = 0; r < 4; r++){
      int d = (m4 << 4) + mi * 16 + quad * 4 + r;
      #pragma unroll
      for (int ei = 0; ei < 4; ei++)
        op[d * 128 + (e4 << 4) + ei * 16 + nn] = acc[mi][ei][r];
    }
  }
}

// ---------------------------------------------------------------- kk reduce + scale + pack to fp8 B tiles
__global__ __launch_bounds__(256) void kkred_kernel(
    const float* __restrict__ kkp, u8* __restrict__ kkbb8)
{
  int item = blockIdx.x * 256 + threadIdx.x;
  int nn = item & 15, d8 = (item >> 4) & 15, os = (item >> 8) & 7, n = item >> 11;
  int e = os * 16 + nn;
  float fv[8];
  #pragma unroll
  for (int j = 0; j < 8; j++){
    float s = 0.f;
    #pragma unroll
    for (int sp = 0; sp < 4; sp++)
      s += kkp[(size_t)sp * (64 * 16384) + n * 16384 + (d8 * 8 + j) * 128 + e];
    fv[j] = s * (SCALEF * 2.f);
  }
  *(uint2*)&kkbb8[((size_t)n << 14) + foff(os, d8, nn)] = pack_fp8x8(fv);
}

// ---------------------------------------------------------------- gateout: all-fp8 MFMA -> outt fp8 frag-major
__global__ __launch_bounds__(256, 4) void gateout_kernel(
    const u8* __restrict__ qt8, const u8* __restrict__ vt8,
    const u8* __restrict__ kkbb8, const u8* __restrict__ w2tb8,
    const float* __restrict__ c2, u8* __restrict__ outt8)
{
  __shared__ __attribute__((aligned(16))) u8 q_s8[64 * 144];  // fp8 q; reused as st8
  __shared__ __attribute__((aligned(16))) u8 v_s8[8192];
  const int tid = threadIdx.x;
  const int lb = blockIdx.x;   // 0..63
  const int n  = blockIdx.y;   // 0..63
  const int l0 = lb * 64;
  const int lane = tid & 63, wv = tid >> 6;
  const int nn = lane & 15, quad = lane >> 4;
  const size_t vtile = ((size_t)(n * 64 + lb)) << 13;
  const size_t qbase = ((size_t)n * L + l0) * 128;

  #pragma unroll
  for (int it = 0; it < 4; it++){
    int item = tid + 256 * it;               // 1024 items x 8B
    int d8b = item & 15, l = item >> 4;
    *(uint2*)&q_s8[l * 144 + d8b * 8] = *(const uint2*)&qt8[qbase + (size_t)l * 128 + d8b * 8];
  }
  #pragma unroll
  for (int it = 0; it < 2; it++){
    int idx = (tid + 256 * it) << 4;
    *(uint4*)&v_s8[idx] = *(const uint4*)&vt8[vtile + idx];
  }
  __syncthreads();

  long aq[4], av[4];
  #pragma unroll
  for (int dc = 0; dc < 4; dc++){
    aq[dc] = *(const long*)&q_s8[(wv * 16 + nn) * 144 + ((dc << 2) + quad) * 8];
    av[dc] = *(const long*)&v_s8[foff(wv, (dc << 2) + quad, nn)];
  }
  const u8* kb8 = kkbb8 + ((size_t)n << 14);
  f32x4 acc_o[8], acc_g[8];
  #pragma unroll
  for (int os = 0; os < 8; os++){ acc_o[os] = (f32x4){0,0,0,0}; acc_g[os] = (f32x4){0,0,0,0}; }
  #pragma unroll
  for (int os = 0; os < 8; os++){
    #pragma unroll
    for (int dc = 0; dc < 4; dc++){
      int d8 = (dc << 2) + quad;
      long bkk = *(const long*)&kb8[foff(os, d8, nn)];
      long bw8 = *(const long*)&w2tb8[foff(os, d8, nn)];
      acc_o[os] = __builtin_amdgcn_mfma_f32_16x16x32_fp8_fp8(av[dc], bkk, acc_o[os], 0, 0, 0);
      acc_g[os] = __builtin_amdgcn_mfma_f32_16x16x32_fp8_fp8(aq[dc], bw8, acc_g[os], 0, 0, 0);
    }
  }
  __syncthreads();   // q_s8 reads done -> reuse as st8
  u8* st8 = q_s8;
  #pragma unroll
  for (int os = 0; os < 8; os++){
    int e = (os << 4) + nn;
    float c2v = c2[e];
    #pragma unroll
    for (int r = 0; r < 4; r++){
      int xr = wv * 16 + quad * 4 + r;
      float ve = e2f(v_s8[faddr(xr, e)]);
      float val = acc_o[os][r] * (1.f / 32.f) + sigmoidf(acc_g[os][r] * 0.0625f + c2v) * ve;
      st8[faddr(xr, e)] = f2e(val);
    }
  }
  __syncthreads();
  #pragma unroll
  for (int it = 0; it < 2; it++){
    int idx = (tid + 256 * it) << 4;
    *(uint4*)&outt8[vtile + idx] = *(const uint4*)&st8[idx];
  }
}

// ---------------------------------------------------------------- outw: fp8 MFMA + bias + residual + LN2 -> xn2b fp8
__global__ __launch_bounds__(256, 4) void outw_kernel(
    const u8* __restrict__ outt8, const u8* __restrict__ wpk8o,
    const float* __restrict__ out_b, const float* __restrict__ x,
    const float* __restrict__ g2, const float* __restrict__ bt2,
    float* __restrict__ x2, u8* __restrict__ xn2b8)
{
  __shared__ float stf[128 * 68];
  const int tid = threadIdx.x;
  const int lb = blockIdx.x;   // 64
  const int b  = blockIdx.y;   // 8
  const int l0 = lb * 64;
  const int lane = tid & 63, wv = tid >> 6;
  const int nn = lane & 15, quad = lane >> 4;
  f32x4 acc[8];
  #pragma unroll
  for (int os = 0; os < 8; os++) acc[os] = (f32x4){0,0,0,0};

  for (int h = 0; h < 8; h++){
    const size_t tbase = ((size_t)((b * 8 + h) * 64 + lb)) << 13;
    long af[4];
    #pragma unroll
    for (int dc = 0; dc < 4; dc++)
      af[dc] = *(const long*)&outt8[tbase + foff(wv, (dc << 2) + quad, nn)];
    const u8* bp8 = wpk8o + (h << 14);
    #pragma unroll
    for (int os = 0; os < 8; os++){
      #pragma unroll
      for (int dc = 0; dc < 4; dc++){
        long bf8 = *(const long*)&bp8[foff(os, (dc << 2) + quad, nn)];
        acc[os] = __builtin_amdgcn_mfma_f32_16x16x32_fp8_fp8(af[dc], bf8, acc[os], 0, 0, 0);
      }
    }
  }
  #pragma unroll
  for (int os = 0; os < 8; os++)
    #pragma unroll
    for (int r = 0; r < 4; r++)
      stf[((os << 4) + nn) * 68 + wv * 16 + quad * 4 + r] = acc[os][r] * 0.0625f;
  __syncthreads();
  {
    int o = tid >> 1, lh = tid & 1;
    float bias = out_b[o];
    size_t gbase = ((size_t)b * 128 + o) * L + l0 + lh * 32;
    float* sp = &stf[o * 68 + lh * 32];
    #pragma unroll
    for (int k = 0; k < 8; k++){
      float4 xv = *(const float4*)&x[gbase + k * 4];
      float4 sv = *(float4*)&sp[k * 4];
      float4 ov = make_float4(sv.x + bias + xv.x, sv.y + bias + xv.y,
                              sv.z + bias + xv.z, sv.w + bias + xv.w);
      *(float4*)&sp[k * 4] = ov;
      *(float4*)&x2[gbase + k * 4] = ov;
    }
  }
  __syncthreads();
  {
    int l = tid >> 2, part = tid & 3;
    float vv[32];
    float s = 0.f, ss = 0.f;
    #pragma unroll
    for (int i = 0; i < 32; i++){
      float v = stf[(part * 32 + i) * 68 + l];
      vv[i] = v; s += v; ss += v * v;
    }
    s += __shfl_xor(s, 1);  s += __shfl_xor(s, 2);
    ss += __shfl_xor(ss, 1); ss += __shfl_xor(ss, 2);
    float m = s * (1.f / 128.f);
    float rs = rsqrtf(ss * (1.f / 128.f) - m * m + EPS);
    #pragma unroll
    for (int c = 0; c < 4; c++){
      float fv[8];
      #pragma unroll
      for (int j = 0; j < 8; j++){
        int d = part * 32 + c * 8 + j;
        fv[j] = (vv[c * 8 + j] - m) * rs * g2[d] + bt2[d];
      }
      *(uint2*)&xn2b8[((size_t)b * L + l0 + l) * 128 + part * 32 + c * 8] = pack_fp8x8(fv);
    }
  }
}

// ---------------------------------------------------------------- ff_fused: fp8 ff1 + gelu -> bf16 LDS -> bf16 ff2 + bias + residual
__global__ __launch_bounds__(256, 4) void ff_fused_kernel(
    const u8* __restrict__ xn2b8, const u8* __restrict__ wpk8,
    const u16* __restrict__ wpk,
    const float* __restrict__ b1, const float* __restrict__ b2,
    const float* __restrict__ x2, float* __restrict__ outp)
{
  __shared__ __attribute__((aligned(16))) u8 a_s8[64 * 136];
  __shared__ u16 h_s[64 * 136];   // gelu(h) bf16; aliased as f32 epilogue stf
  const int tid = threadIdx.x;
  const int lb = blockIdx.x;   // 64
  const int b  = blockIdx.y;   // 8
  const int l0 = lb * 64;
  const int lane = tid & 63, wv = tid >> 6;
  const int nn = lane & 15, quad = lane >> 4;

  #pragma unroll
  for (int it = 0; it < 4; it++){
    int item = tid + 256 * it;
    int d8 = item & 15, l = item >> 4;
    *(uint2*)&a_s8[l * 136 + d8 * 8] =
        *(const uint2*)&xn2b8[((size_t)b * L + l0 + l) * 128 + d8 * 8];
  }
  __syncthreads();
  long af8[4];
  #pragma unroll
  for (int dc = 0; dc < 4; dc++)
    af8[dc] = *(const long*)&a_s8[(wv * 16 + nn) * 136 + ((dc << 2) + quad) * 8];

  f32x4 acc_out[8];
  #pragma unroll
  for (int os = 0; os < 8; os++) acc_out[os] = (f32x4){0.f, 0.f, 0.f, 0.f};

  for (int fc = 0; fc < 4; fc++){
    const u8* bp1 = wpk8 + (size_t)(32 + fc) * 16384;
    f32x4 hacc[8];
    #pragma unroll
    for (int os = 0; os < 8; os++) hacc[os] = (f32x4){0.f, 0.f, 0.f, 0.f};
    #pragma unroll
    for (int os = 0; os < 8; os++){
      #pragma unroll
      for (int dc = 0; dc < 4; dc++){
        long bf8 = *(const long*)&bp1[foff(os, (dc << 2) + quad, nn)];
        hacc[os] = __builtin_amdgcn_mfma_f32_16x16x32_fp8_fp8(af8[dc], bf8, hacc[os], 0, 0, 0);
      }
    }
    __syncthreads();   // h_s free (prev hf readers done)
    #pragma unroll
    for (int os = 0; os < 8; os++){
      float bias = b1[fc * 128 + (os << 4) + nn];
      #pragma unroll
      for (int r = 0; r < 4; r++){
        float v = hacc[os][r] * 0.0625f + bias;
        float ge = 0.5f * v * (1.f + erff(v * 0.70710678118654752f));
        h_s[(wv * 16 + quad * 4 + r) * 136 + (os << 4) + nn] = f2b(ge);
      }
    }
    __syncthreads();
    bf16x8 hf[4];
    #pragma unroll
    for (int dc = 0; dc < 4; dc++)
      hf[dc] = *(const bf16x8*)&h_s[(wv * 16 + nn) * 136 + ((dc << 2) + quad) * 8];
    const u16* bp2 = wpk + (size_t)(36 + fc) * 16384;
    #pragma unroll
    for (int os = 0; os < 8; os++){
      #pragma unroll
      for (int dc = 0; dc < 4; dc++){
        int d8 = (dc << 2) + quad;
        bf16x8 bf = *(const bf16x8*)&bp2[(os << 11) + (d8 << 7) + ((nn ^ d8) << 3)];
        acc_out[os] = __builtin_amdgcn_mfma_f32_16x16x32_bf16(hf[dc], bf, acc_out[os], 0, 0, 0);
      }
    }
  }

  float* stf = (float*)h_s;
  #pragma unroll
  for (int t = 0; t < 2; t++){
    __syncthreads();
    #pragma unroll
    for (int osl = 0; osl < 4; osl++){
      int os = t * 4 + osl;
      #pragma unroll
      for (int r = 0; r < 4; r++)
        stf[((osl << 4) + nn) * 68 + wv * 16 + quad * 4 + r] = acc_out[os][r];
    }
    __syncthreads();
    int ol = tid >> 2;
    int o  = t * 64 + ol;
    int lc = (tid & 3) * 16;
    float bias = b2[o];
    size_t gbase = ((size_t)b * 128 + o) * L + l0 + lc;
    #pragma unroll
    for (int k = 0; k < 4; k++){
      float4 sv = *(const float4*)&stf[ol * 68 + lc + k * 4];
      float4 xv = *(const float4*)&x2[gbase + k * 4];
      *(float4*)&outp[gbase + k * 4] = make_float4(sv.x + bias + xv.x, sv.y + bias + xv.y,
                                                   sv.z + bias + xv.z, sv.w + bias + xv.w);
    }
  }
}

} // namespace

extern "C" void kernel_launch(void* const* d_in, const int* in_sizes, int n_in,
                              void* d_out, int out_size, void* d_ws, size_t ws_size,
                              hipStream_t stream)
{
  const float* x      = (const float*)d_in[0];
  const float* ln1_g  = (const float*)d_in[1];
  const float* ln1_b  = (const float*)d_in[2];
  const float* q_dw   = (const float*)d_in[3];
  const float* q_bng  = (const float*)d_in[4];
  const float* q_bnb  = (const float*)d_in[5];
  const float* q_bnm  = (const float*)d_in[6];
  const float* q_bnv  = (const float*)d_in[7];
  const float* q_pw   = (const float*)d_in[8];
  const float* k_dw   = (const float*)d_in[9];
  const float* k_bng  = (const float*)d_in[10];
  const float* k_bnb  = (const float*)d_in[11];
  const float* k_bnm  = (const float*)d_in[12];
  const float* k_bnv  = (const float*)d_in[13];
  const float* k_pw   = (const float*)d_in[14];
  const float* v_dw   = (const float*)d_in[15];
  const float* v_bng  = (const float*)d_in[16];
  const float* v_bnb  = (const float*)d_in[17];
  const float* v_bnm  = (const float*)d_in[18];
  const float* v_bnv  = (const float*)d_in[19];
  const float* v_pw   = (const float*)d_in[20];
  const float* dwc_dw  = (const float*)d_in[21];
  const float* dwc_bng = (const float*)d_in[22];
  const float* dwc_bnb = (const float*)d_in[23];
  const float* dwc_bnm = (const float*)d_in[24];
  const float* dwc_bnv = (const float*)d_in[25];
  const float* dwc_pw  = (const float*)d_in[26];
  const float* out_w  = (const float*)d_in[27];
  const float* out_b  = (const float*)d_in[28];
  const float* ln2_g  = (const float*)d_in[29];
  const float* ln2_b  = (const float*)d_in[30];
  const float* ff_w1  = (const float*)d_in[31];
  const float* ff_b1  = (const float*)d_in[32];
  const float* ff_w2  = (const float*)d_in[33];
  const float* ff_b2  = (const float*)d_in[34];
  float* out = (float*)d_out;

  // ---- workspace layout (lifetime-aliased) ----
  // [0,32M)    qt8 fp8            (qkv .. gateout)
  // [32,64M)   kt8 fp8            (qkv .. kk)
  // [64,96M)   outt8 fp8          (gateout .. outw)
  // [128,160M) vt8 fp8            (qkv .. gateout)
  // [192,200M) xnb bf16 (prep..qkv) -> kkbb8 1MB (kkred..gateout) -> xn2b8 fp8 4MB (outw..ff)
  // [200,216M) kkp 16MB (kk..kkred) -> x2 16MB (outw..ff)
  // [216M..)   c2 + wpk bf16 (ff_w2 tiles); wpk8 fp8 37 tiles @218M
  char* w = (char*)d_ws;
  u8*   qt8   = (u8*)(w);
  u8*   kt8   = (u8*)(w + (32ull  << 20));
  u8*   outt8 = (u8*)(w + (64ull  << 20));
  u8*   vt8   = (u8*)(w + (128ull << 20));
  u16*  xnb   = (u16*)(w + (192ull << 20));
  u8*   kkbb8 = (u8*)(w + (192ull << 20));
  u8*   xn2b8 = (u8*)(w + (192ull << 20));
  float* kkp  = (float*)(w + (200ull << 20));
  float* x2   = kkp;
  float* c2   = (float*)(w + (216ull << 20));
  u16*  wpk   = (u16*)(w + (216ull << 20) + 65536);
  u8*   wpk8  = (u8*)(w + (218ull << 20));
  u8*   wpk8o = wpk8 + ((size_t)24 << 14);   // out_w tiles
  u8*   w2tb8 = wpk8 + ((size_t)36 << 14);   // gate pw tile

  prep_kernel<<<582, 256, 0, stream>>>(x, ln1_g, ln1_b, xnb,
                                       q_pw, k_pw, v_pw, out_w, ff_w1, ff_w2,
                                       dwc_dw, dwc_bng, dwc_bnv, dwc_bnb, dwc_bnm, dwc_pw,
                                       wpk, c2, wpk8);

  QkvArgs qa;
  qa.dw[0] = q_dw;  qa.bng[0] = q_bng; qa.bnb[0] = q_bnb; qa.bnm[0] = q_bnm; qa.bnv[0] = q_bnv; qa.outp[0] = qt8;
  qa.dw[1] = k_dw;  qa.bng[1] = k_bng; qa.bnb[1] = k_bnb; qa.bnm[1] = k_bnm; qa.bnv[1] = k_bnv; qa.outp[1] = kt8;
  qa.dw[2] = v_dw;  qa.bng[2] = v_bng; qa.bnb[2] = v_bnb; qa.bnm[2] = v_bnm; qa.bnv[2] = v_bnv; qa.outp[2] = vt8;
  qkv_fused_kernel<<<dim3(64, 24), 256, 0, stream>>>(xnb, wpk8, qa);

  kk_kernel<<<dim3(4, 64), 256, 0, stream>>>(qt8, kt8, kkp);
  kkred_kernel<<<512, 256, 0, stream>>>(kkp, kkbb8);
  gateout_kernel<<<dim3(64, 64), 256, 0, stream>>>(qt8, vt8, kkbb8, w2tb8, c2, outt8);
  outw_kernel<<<dim3(64, 8), 256, 0, stream>>>(outt8, wpk8o, out_b, x, ln2_g, ln2_b, x2, xn2b8);

  ff_fused_kernel<<<dim3(64, 8), 256, 0, stream>>>(xn2b8, wpk8, wpk, ff_b1, ff_b2, x2, out);
}